// Round 10
// baseline (345.920 us; speedup 1.0000x reference)
//
#include <hip/hip_runtime.h>
#include <hip/hip_bf16.h>

typedef __hip_bfloat16 bf16;
typedef __attribute__((ext_vector_type(8))) short short8;
typedef __attribute__((ext_vector_type(8))) __bf16 bf16x8;
typedef __attribute__((ext_vector_type(4))) float f32x4;

#define BN 20736      // 256*81
#define NNODE 81
#define KNB 20

__device__ inline float bf2f(short s) {
  union { unsigned u; float f; } x; x.u = ((unsigned)(unsigned short)s) << 16; return x.f;
}
__device__ inline short f2bf(float f) {
  __hip_bfloat16 h = __float2bfloat16(f);
  return *reinterpret_cast<short*>(&h);
}
__device__ inline bf16x8 ld8(const bf16* p) {
  return __builtin_bit_cast(bf16x8, *(const short8*)p);
}

// ---------- 48-col helpers (fused_in, edge) ----------
__device__ inline void zacc3(f32x4 acc[3]) {
  #pragma unroll
  for (int nt = 0; nt < 3; ++nt) acc[nt] = (f32x4){0.f, 0.f, 0.f, 0.f};
}
__device__ inline void load_w48(const bf16* __restrict__ W, int ldw, int n0, int lr, int lq,
                                bf16x8 wf[3][3]) {
  #pragma unroll
  for (int nt = 0; nt < 3; ++nt)
    #pragma unroll
    for (int ks = 0; ks < 3; ++ks)
      wf[nt][ks] = ld8(&W[(size_t)(n0 + nt * 16 + lr) * ldw + ks * 32 + lq * 8]);
}
__device__ inline void gemm48(const bf16x8 af[3], const bf16x8 wf[3][3], f32x4 acc[3]) {
  #pragma unroll
  for (int ks = 0; ks < 3; ++ks)
    #pragma unroll
    for (int nt = 0; nt < 3; ++nt)
      acc[nt] = __builtin_amdgcn_mfma_f32_16x16x32_bf16(af[ks], wf[nt][ks], acc[nt], 0, 0, 0);
}
__device__ inline void acc_store_cs(float* xw, const f32x4 acc[3], int lr, int lq, int n0) {
  #pragma unroll
  for (int nt = 0; nt < 3; ++nt)
    #pragma unroll
    for (int r = 0; r < 4; ++r)
      xw[(lq * 4 + r) * 100 + n0 + nt * 16 + lr] = acc[nt][r];
}
// ---------- 16-col helpers (fused_iter) ----------
__device__ inline void load_w16(const bf16* __restrict__ W, int ldw, int n0, int lr, int lq,
                                bf16x8 wf[3]) {
  #pragma unroll
  for (int ks = 0; ks < 3; ++ks)
    wf[ks] = ld8(&W[(size_t)(n0 + lr) * ldw + ks * 32 + lq * 8]);
}
__device__ inline void gemm16(const bf16x8 af[3], const bf16x8 wf[3], f32x4& acc) {
  #pragma unroll
  for (int ks = 0; ks < 3; ++ks)
    acc = __builtin_amdgcn_mfma_f32_16x16x32_bf16(af[ks], wf[ks], acc, 0, 0, 0);
}
// full-width frag read from f32 xbuf with epilogue
__device__ inline void xbuf_frag(const float* xw, int lr, int lq,
                                 const float* __restrict__ bias, float bscale,
                                 const bf16* residRow, int act,
                                 bf16x8 af[3]) {
  #pragma unroll
  for (int ks = 0; ks < 3; ++ks) {
    const int c0 = ks * 32 + lq * 8;
    float4 x0 = *(const float4*)&xw[lr * 100 + c0];
    float4 x1 = *(const float4*)&xw[lr * 100 + c0 + 4];
    float xv[8] = {x0.x, x0.y, x0.z, x0.w, x1.x, x1.y, x1.z, x1.w};
    if (bias) {
      float4 b0 = *(const float4*)&bias[c0];
      float4 b1 = *(const float4*)&bias[c0 + 4];
      float bv[8] = {b0.x, b0.y, b0.z, b0.w, b1.x, b1.y, b1.z, b1.w};
      #pragma unroll
      for (int j = 0; j < 8; ++j) xv[j] += bscale * bv[j];
    }
    if (residRow) {
      short8 r8 = *(const short8*)&residRow[c0];
      #pragma unroll
      for (int j = 0; j < 8; ++j) xv[j] += bf2f(r8[j]);
    }
    short8 o;
    #pragma unroll
    for (int j = 0; j < 8; ++j) {
      float v = xv[j];
      if (act) v = fmaxf(v, 0.f);
      o[j] = f2bf(v);
    }
    af[ks] = __builtin_bit_cast(bf16x8, o);
  }
}
__device__ inline void store_frag(bf16* dst, int lq, const bf16x8 af[3]) {
  #pragma unroll
  for (int ks = 0; ks < 3; ++ks)
    *(short8*)&dst[ks * 32 + lq * 8] = __builtin_bit_cast(short8, af[ks]);
}

// ================= prologue: convert/build all weights =================
__global__ __launch_bounds__(256) void prep_k(
    const float* in_w1, const float* in_w2, const float* f_w1, const float* f_w2,
    const float* g_w1, const float* g_w2, const float* r_w0, const float* r_w1,
    const float* r_w2, const float* wih, const float* whh, const float* g_w0,
    const float* f_w0, const float* in_w0, const float* f_b0,
    bf16* inw1b, bf16* inw2b, bf16* fw1b, bf16* fw2b,
    bf16* gw1b, bf16* gw2b, bf16* rw0b, bf16* rw1b,
    bf16* rw2b, bf16* wihb, bf16* whhb, bf16* gw0b,
    bf16* wfnb, bf16* w0pb, float* bias_fn)
{
  int idx = blockIdx.x * 256 + threadIdx.x;
  int y = blockIdx.y;
  const float* src = nullptr; bf16* dst = nullptr; int cnt = 0;
  switch (y) {
    case 0:  src = in_w1; dst = inw1b; cnt = 9216;  break;
    case 1:  src = in_w2; dst = inw2b; cnt = 9216;  break;
    case 2:  src = f_w1;  dst = fw1b;  cnt = 9216;  break;
    case 3:  src = f_w2;  dst = fw2b;  cnt = 9216;  break;
    case 4:  src = g_w1;  dst = gw1b;  cnt = 9216;  break;
    case 5:  src = g_w2;  dst = gw2b;  cnt = 9216;  break;
    case 6:  src = r_w0;  dst = rw0b;  cnt = 9216;  break;
    case 7:  src = r_w1;  dst = rw1b;  cnt = 9216;  break;
    case 8:  src = r_w2;  dst = rw2b;  cnt = 864;   break;
    case 9:  src = wih;   dst = wihb;  cnt = 36864; break;
    case 10: src = whh;   dst = whhb;  cnt = 36864; break;
    case 11: src = g_w0;  dst = gw0b;  cnt = 18432; break;
    case 12: {
      if (idx < 18432) {
        int n = idx / 96, k = idx - n * 96;
        float v = (n < 96) ? f_w0[n * 192 + k] : f_w0[(n - 96) * 192 + 96 + k];
        wfnb[idx] = __float2bfloat16(v);
      }
      return;
    }
    case 13: {
      if (idx < 3072) {
        int n = idx >> 5, k = idx & 31;
        w0pb[idx] = __float2bfloat16(k < 16 ? in_w0[n * 16 + k] : 0.f);
      }
      return;
    }
    default: {
      if (idx < 192) bias_fn[idx] = (idx < 96) ? f_b0[idx] : 0.f;
      return;
    }
  }
  if (idx < cnt) dst[idx] = __float2bfloat16(src[idx]);
}

__global__ __launch_bounds__(256) void embed_k(const float* __restrict__ embed,
                                               const int* __restrict__ grids,
                                               bf16* __restrict__ emb) {
  int idx = blockIdx.x * 256 + threadIdx.x;
  if (idx >= BN * 32) return;
  int r = idx >> 5, k = idx & 31;
  emb[idx] = __float2bfloat16(k < 16 ? embed[grids[r] * 16 + k] : 0.f);
}

// ================= fused input chain (unchanged from R9) =================
__global__ __launch_bounds__(256) void fused_in_k(
    const bf16* __restrict__ emb, const bf16* __restrict__ w0pb, const float* __restrict__ in_b0,
    const bf16* __restrict__ inw1b, const float* __restrict__ in_b1,
    const bf16* __restrict__ inw2b, const float* __restrict__ in_b2,
    const bf16* __restrict__ gw0b, const float* __restrict__ g_b0,
    const bf16* __restrict__ wfnb, const float* __restrict__ bias_fn,
    bf16* __restrict__ X, bf16* __restrict__ Xg, bf16* __restrict__ P)
{
  __shared__ float xbuf[2][2][1600];
  const int t = threadIdx.x, w = t >> 6, lane = t & 63, lr = lane & 15, lq = lane >> 4;
  const int mh = w >> 1, ch = w & 1, n0 = ch * 48;
  const int m0 = blockIdx.x * 32 + mh * 16;
  float* x0 = xbuf[0][mh];
  float* x1 = xbuf[1][mh];
  bf16x8 wf[3][3]; f32x4 acc[3]; bf16x8 af[3];

  bf16x8 a0 = ld8(&emb[(size_t)(m0 + lr) * 32 + lq * 8]);
  #pragma unroll
  for (int nt = 0; nt < 3; ++nt)
    wf[nt][0] = ld8(&w0pb[(size_t)(n0 + nt * 16 + lr) * 32 + lq * 8]);
  zacc3(acc);
  #pragma unroll
  for (int nt = 0; nt < 3; ++nt)
    acc[nt] = __builtin_amdgcn_mfma_f32_16x16x32_bf16(a0, wf[nt][0], acc[nt], 0, 0, 0);
  acc_store_cs(x0, acc, lr, lq, n0);
  __syncthreads();
  xbuf_frag(x0, lr, lq, in_b0, 1.f, nullptr, 1, af);
  load_w48(inw1b, 96, n0, lr, lq, wf); zacc3(acc); gemm48(af, wf, acc);
  acc_store_cs(x1, acc, lr, lq, n0);
  __syncthreads();
  xbuf_frag(x1, lr, lq, in_b1, 1.f, nullptr, 1, af);
  load_w48(inw2b, 96, n0, lr, lq, wf); zacc3(acc); gemm48(af, wf, acc);
  acc_store_cs(x0, acc, lr, lq, n0);
  __syncthreads();
  bf16x8 xf[3];
  xbuf_frag(x0, lr, lq, in_b2, 1.f, nullptr, 0, xf);
  if (ch == 0) store_frag(&X[(size_t)(m0 + lr) * 96], lq, xf);
  load_w48(gw0b, 192, n0, lr, lq, wf); zacc3(acc); gemm48(xf, wf, acc);
  acc_store_cs(x1, acc, lr, lq, n0);
  __syncthreads();
  xbuf_frag(x1, lr, lq, g_b0, 1.f, nullptr, 0, af);
  if (ch == 0) store_frag(&Xg[(size_t)(m0 + lr) * 96], lq, af);
  #pragma unroll
  for (int ph = 0; ph < 2; ++ph) {
    float* xb = ph ? x1 : x0;
    load_w48(wfnb + (size_t)ph * 96 * 96, 96, n0, lr, lq, wf); zacc3(acc); gemm48(xf, wf, acc);
    acc_store_cs(xb, acc, lr, lq, n0);
    __syncthreads();
    xbuf_frag(xb, lr, lq, bias_fn + ph * 96, 1.f, nullptr, 0, af);
    if (ch == 0) store_frag(&P[(size_t)(m0 + lr) * 192 + ph * 96], lq, af);
  }
}

// ================= edge kernel (R9 + XCD-chunked swizzle) =================
__global__ __launch_bounds__(256) void edge_k(
    const bf16* __restrict__ P, const bf16* __restrict__ w1bf,
    const float* __restrict__ b1, const int* __restrict__ edges,
    const bf16* __restrict__ fw2b, const float* __restrict__ f_b2,
    bf16* __restrict__ M)
{
  __shared__ short zs[160 * 104];
  __shared__ short sbuf[16 * 104];
  const int t = threadIdx.x;
  // 2592 blocks = 8 * 324: chunk-per-XCD swizzle (bijective)
  const int swz = (blockIdx.x & 7) * 324 + (blockIdx.x >> 3);
  const int ng0 = swz * 2;
  for (int i = t; i < 8 * 104; i += 256) sbuf[(8 + i / 104) * 104 + (i % 104)] = 0;
  for (int cc = t; cc < 160 * 12; cc += 256) {
    int zrow = cc / 12, c8 = cc - zrow * 12;
    int g = zrow >= 80 ? 1 : 0;
    int row = zrow - g * 80;
    int p = row / 20, j = row - p * 20;
    int gr = (ng0 + g) * 4 + p;
    int b = gr / NNODE, i = gr - b * NNODE;
    int e = edges[i * KNB + j];
    short8 a8 = *(const short8*)&P[(size_t)gr * 192 + c8 * 8];
    short8 n8 = *(const short8*)&P[((size_t)b * NNODE + e) * 192 + 96 + c8 * 8];
    short8 z;
    #pragma unroll
    for (int q = 0; q < 8; ++q)
      z[q] = f2bf(fmaxf(bf2f(a8[q]) + bf2f(n8[q]), 0.f));
    *(short8*)&zs[zrow * 104 + c8 * 8] = z;
  }
  __syncthreads();

  const int w = t >> 6, lane = t & 63, lr = lane & 15, lq = lane >> 4;
  const int g = w >> 1, ch = w & 1, n0 = ch * 48, zb = g * 80;

  bf16x8 wf[3][3];
  #pragma unroll
  for (int nt = 0; nt < 3; ++nt)
    #pragma unroll
    for (int ks = 0; ks < 3; ++ks)
      wf[nt][ks] = ld8(&w1bf[(size_t)(n0 + nt * 16 + lr) * 96 + ks * 32 + lq * 8]);

  f32x4 acc[5][3];
  #pragma unroll
  for (int mt = 0; mt < 5; ++mt)
    #pragma unroll
    for (int nt = 0; nt < 3; ++nt) acc[mt][nt] = (f32x4){0.f, 0.f, 0.f, 0.f};

  #pragma unroll
  for (int ks = 0; ks < 3; ++ks) {
    const int koff = ks * 32 + lq * 8;
    #pragma unroll
    for (int mt = 0; mt < 5; ++mt) {
      bf16x8 af = __builtin_bit_cast(bf16x8, *(const short8*)&zs[(zb + mt * 16 + lr) * 104 + koff]);
      #pragma unroll
      for (int nt = 0; nt < 3; ++nt)
        acc[mt][nt] = __builtin_amdgcn_mfma_f32_16x16x32_bf16(af, wf[nt][ks], acc[mt][nt], 0, 0, 0);
    }
  }

  float bv[3];
  #pragma unroll
  for (int nt = 0; nt < 3; ++nt) bv[nt] = b1[n0 + nt * 16 + lr];
  float nodeacc[4][3];
  #pragma unroll
  for (int pp = 0; pp < 4; ++pp)
    #pragma unroll
    for (int nt = 0; nt < 3; ++nt) nodeacc[pp][nt] = 0.f;
  #pragma unroll
  for (int mt = 0; mt < 5; ++mt)
    #pragma unroll
    for (int nt = 0; nt < 3; ++nt)
      #pragma unroll
      for (int r = 0; r < 4; ++r) {
        int row = mt * 16 + lq * 4 + r;
        int p = row / 20;
        float v = fmaxf(acc[mt][nt][r] + bv[nt], 0.f);
        #pragma unroll
        for (int pp = 0; pp < 4; ++pp)
          nodeacc[pp][nt] += (p == pp) ? v : 0.f;
      }
  #pragma unroll
  for (int pp = 0; pp < 4; ++pp)
    #pragma unroll
    for (int nt = 0; nt < 3; ++nt) {
      float v = nodeacc[pp][nt];
      v += __shfl_xor(v, 16, 64);
      v += __shfl_xor(v, 32, 64);
      if (lq == 0)
        sbuf[(g * 4 + pp) * 104 + n0 + nt * 16 + lr] = f2bf(v);
    }
  __syncthreads();
  if (w < 2) {
    const int mn0 = w * 48;
    bf16x8 mwf[3][3];
    #pragma unroll
    for (int nt = 0; nt < 3; ++nt)
      #pragma unroll
      for (int ks = 0; ks < 3; ++ks)
        mwf[nt][ks] = ld8(&fw2b[(size_t)(mn0 + nt * 16 + lr) * 96 + ks * 32 + lq * 8]);
    f32x4 macc[3];
    zacc3(macc);
    #pragma unroll
    for (int ks = 0; ks < 3; ++ks) {
      bf16x8 af = __builtin_bit_cast(bf16x8, *(const short8*)&sbuf[lr * 104 + ks * 32 + lq * 8]);
      #pragma unroll
      for (int nt = 0; nt < 3; ++nt)
        macc[nt] = __builtin_amdgcn_mfma_f32_16x16x32_bf16(af, mwf[nt][ks], macc[nt], 0, 0, 0);
    }
    #pragma unroll
    for (int nt = 0; nt < 3; ++nt) {
      int col = mn0 + nt * 16 + lr;
      float bb = (float)KNB * f_b2[col];
      #pragma unroll
      for (int r = 0; r < 4; ++r) {
        int row = lq * 4 + r;
        if (row < 8)
          M[(size_t)(ng0 * 4 + row) * 96 + col] = __float2bfloat16(macc[nt][r] + bb);
      }
    }
  }
}

// ===== fused iteration kernel: 6-way col-split, 16 rows/block, 6 waves =====
__global__ __launch_bounds__(384) void fused_iter_k(
    const bf16* __restrict__ Min,
    const bf16* __restrict__ gw0b, const bf16* __restrict__ Xg,
    const bf16* __restrict__ gw1b, const float* __restrict__ g_b1,
    const bf16* __restrict__ gw2b, const float* __restrict__ g_b2,
    const bf16* __restrict__ Hin,
    const bf16* __restrict__ wihb, const bf16* __restrict__ whhb,
    const float* __restrict__ bih, const float* __restrict__ bhh,
    float* __restrict__ c, bf16* __restrict__ Hout,
    const bf16* __restrict__ wfnb, const float* __restrict__ bias_fn, bf16* __restrict__ P,
    const bf16* __restrict__ rw0b, const float* __restrict__ r_b0,
    const bf16* __restrict__ rw1b, const float* __restrict__ r_b1,
    const bf16* __restrict__ rw2b, const float* __restrict__ r_b2,
    float* __restrict__ outp, int doP)
{
  __shared__ short ab[3][16 * 104];     // staged Min, Xg, Hin rows (bf16)
  __shared__ float xb0[1600], xb1[1600];
  const int t = threadIdx.x, w = t >> 6, lane = t & 63, lr = lane & 15, lq = lane >> 4;
  const int n0 = w * 16;                // this wave's 16-col slice
  const int m0 = blockIdx.x * 16;

  // ---- co-op stage A-operands (coalesced) ----
  for (int cc = t; cc < 576; cc += 384) {
    int arr = cc / 192, rem = cc - arr * 192, row = rem / 12, c8 = rem - row * 12;
    const bf16* src = arr == 0 ? Min : (arr == 1 ? Xg : Hin);
    *(short8*)&ab[arr][row * 104 + c8 * 8] =
        *(const short8*)&src[(size_t)(m0 + row) * 96 + c8 * 8];
  }
  __syncthreads();

  bf16x8 wf[3], af[3];
  f32x4 acc;

  // s1: Min @ g_w0[:,96:]^T -> xb0 (raw)
  #pragma unroll
  for (int ks = 0; ks < 3; ++ks)
    af[ks] = ld8((const bf16*)&ab[0][lr * 104 + ks * 32 + lq * 8]);
  load_w16(gw0b + 96, 192, n0, lr, lq, wf);
  acc = (f32x4){0.f, 0.f, 0.f, 0.f}; gemm16(af, wf, acc);
  #pragma unroll
  for (int r = 0; r < 4; ++r) xb0[(lq * 4 + r) * 100 + n0 + lr] = acc[r];
  __syncthreads();
  // s2: z1 = relu(. + Xg); @ g_w1 -> xb1
  xbuf_frag(xb0, lr, lq, nullptr, 0.f, (const bf16*)&ab[1][lr * 104], 1, af);
  load_w16(gw1b, 96, n0, lr, lq, wf);
  acc = (f32x4){0.f, 0.f, 0.f, 0.f}; gemm16(af, wf, acc);
  #pragma unroll
  for (int r = 0; r < 4; ++r) xb1[(lq * 4 + r) * 100 + n0 + lr] = acc[r];
  __syncthreads();
  // s3: z2 = relu(. + g_b1); @ g_w2 -> xb0
  xbuf_frag(xb1, lr, lq, g_b1, 1.f, nullptr, 1, af);
  load_w16(gw2b, 96, n0, lr, lq, wf);
  acc = (f32x4){0.f, 0.f, 0.f, 0.f}; gemm16(af, wf, acc);
  #pragma unroll
  for (int r = 0; r < 4; ++r) xb0[(lq * 4 + r) * 100 + n0 + lr] = acc[r];
  __syncthreads();

  // ---- LSTM: gin frags + Hin frags; 4 gates for this wave's 16 cols ----
  bf16x8 gf[3], hin[3];
  xbuf_frag(xb0, lr, lq, g_b2, 1.f, nullptr, 0, gf);
  #pragma unroll
  for (int ks = 0; ks < 3; ++ks)
    hin[ks] = ld8((const bf16*)&ab[2][lr * 104 + ks * 32 + lq * 8]);
  f32x4 ga[4];
  #pragma unroll
  for (int g4 = 0; g4 < 4; ++g4) ga[g4] = (f32x4){0.f, 0.f, 0.f, 0.f};
  #pragma unroll
  for (int g4 = 0; g4 < 4; ++g4) {
    size_t nrow = (size_t)(g4 * 96 + n0 + lr) * 96;
    #pragma unroll
    for (int ks = 0; ks < 3; ++ks) {
      ga[g4] = __builtin_amdgcn_mfma_f32_16x16x32_bf16(
          gf[ks], ld8(&wihb[nrow + ks * 32 + lq * 8]), ga[g4], 0, 0, 0);
      ga[g4] = __builtin_amdgcn_mfma_f32_16x16x32_bf16(
          hin[ks], ld8(&whhb[nrow + ks * 32 + lq * 8]), ga[g4], 0, 0, 0);
    }
  }
  {
    const int col = n0 + lr;
    float bvi = bih[col] + bhh[col];
    float bvf = bih[96 + col] + bhh[96 + col];
    float bvg = bih[192 + col] + bhh[192 + col];
    float bvo = bih[288 + col] + bhh[288 + col];
    #pragma unroll
    for (int r = 0; r < 4; ++r) {
      int m = m0 + lq * 4 + r;
      size_t idx = (size_t)m * 96 + col;
      float gi = ga[0][r] + bvi;
      float gfv = ga[1][r] + bvf;
      float gg = ga[2][r] + bvg;
      float go = ga[3][r] + bvo;
      float si = 1.f / (1.f + expf(-gi));
      float sf = 1.f / (1.f + expf(-gfv));
      float so = 1.f / (1.f + expf(-go));
      float tg = tanhf(gg);
      float cn = sf * c[idx] + si * tg;
      if (doP) c[idx] = cn;
      xb1[(lq * 4 + r) * 100 + col] = so * tanhf(cn);
    }
  }
  __syncthreads();

  bf16x8 hf[3];
  xbuf_frag(xb1, lr, lq, nullptr, 0.f, nullptr, 0, hf);

  if (doP) {
    // co-op coalesced Hout write from xb1
    if (t < 192) {
      int row = t / 12, c8 = t - row * 12;
      short8 o;
      #pragma unroll
      for (int j = 0; j < 8; ++j) o[j] = f2bf(xb1[row * 100 + c8 * 8 + j]);
      *(short8*)&Hout[(size_t)(m0 + row) * 96 + c8 * 8] = o;
    }
    // P half 0 -> xb0 (biased)
    load_w16(wfnb, 96, n0, lr, lq, wf);
    acc = (f32x4){0.f, 0.f, 0.f, 0.f}; gemm16(hf, wf, acc);
    {
      float bv = bias_fn[n0 + lr];
      #pragma unroll
      for (int r = 0; r < 4; ++r) xb0[(lq * 4 + r) * 100 + n0 + lr] = acc[r] + bv;
    }
    __syncthreads();
    // co-op write P0; P half 1 -> xb1 (biased)
    if (t < 192) {
      int row = t / 12, c8 = t - row * 12;
      short8 o;
      #pragma unroll
      for (int j = 0; j < 8; ++j) o[j] = f2bf(xb0[row * 100 + c8 * 8 + j]);
      *(short8*)&P[(size_t)(m0 + row) * 192 + c8 * 8] = o;
    }
    load_w16(wfnb + 96 * 96, 96, n0, lr, lq, wf);
    acc = (f32x4){0.f, 0.f, 0.f, 0.f}; gemm16(hf, wf, acc);
    {
      float bv = bias_fn[96 + n0 + lr];
      #pragma unroll
      for (int r = 0; r < 4; ++r) xb1[(lq * 4 + r) * 100 + n0 + lr] = acc[r] + bv;
    }
    __syncthreads();
    if (t < 192) {
      int row = t / 12, c8 = t - row * 12;
      short8 o;
      #pragma unroll
      for (int j = 0; j < 8; ++j) o[j] = f2bf(xb1[row * 100 + c8 * 8 + j]);
      *(short8*)&P[(size_t)(m0 + row) * 192 + 96 + c8 * 8] = o;
    }
  }

  // ---- r-MLP ----
  load_w16(rw0b, 96, n0, lr, lq, wf);
  acc = (f32x4){0.f, 0.f, 0.f, 0.f}; gemm16(hf, wf, acc);
  __syncthreads();   // P1 co-op readers (doP) / prior xb0 readers done
  #pragma unroll
  for (int r = 0; r < 4; ++r) xb0[(lq * 4 + r) * 100 + n0 + lr] = acc[r];
  __syncthreads();
  xbuf_frag(xb0, lr, lq, r_b0, 1.f, nullptr, 1, af);
  load_w16(rw1b, 96, n0, lr, lq, wf);
  acc = (f32x4){0.f, 0.f, 0.f, 0.f}; gemm16(af, wf, acc);
  __syncthreads();   // xb1 readers done before overwrite
  #pragma unroll
  for (int r = 0; r < 4; ++r) xb1[(lq * 4 + r) * 100 + n0 + lr] = acc[r];
  __syncthreads();
  xbuf_frag(xb1, lr, lq, r_b1, 1.f, nullptr, 1, af);
  if (w == 0) {
    bf16x8 w9[3];
    #pragma unroll
    for (int ks = 0; ks < 3; ++ks) {
      short8 s = {0, 0, 0, 0, 0, 0, 0, 0};
      if (lr < 9) s = *(const short8*)&rw2b[(size_t)lr * 96 + ks * 32 + lq * 8];
      w9[ks] = __builtin_bit_cast(bf16x8, s);
    }
    f32x4 a9 = (f32x4){0.f, 0.f, 0.f, 0.f};
    #pragma unroll
    for (int ks = 0; ks < 3; ++ks)
      a9 = __builtin_amdgcn_mfma_f32_16x16x32_bf16(af[ks], w9[ks], a9, 0, 0, 0);
    if (lr < 9) {
      float bb = r_b2[lr];
      #pragma unroll
      for (int r = 0; r < 4; ++r)
        outp[(size_t)(m0 + lq * 4 + r) * 9 + lr] = a9[r] + bb;
    }
  }
}

// ================= host side =================
extern "C" void kernel_launch(void* const* d_in, const int* in_sizes, int n_in,
                              void* d_out, int out_size, void* d_ws, size_t ws_size,
                              hipStream_t stream) {
  const float* embed   = (const float*)d_in[0];
  const float* in_w0   = (const float*)d_in[1];
  const float* in_b0   = (const float*)d_in[2];
  const float* in_w1   = (const float*)d_in[3];
  const float* in_b1   = (const float*)d_in[4];
  const float* in_w2   = (const float*)d_in[5];
  const float* in_b2   = (const float*)d_in[6];
  const float* f_w0    = (const float*)d_in[7];
  const float* f_b0    = (const float*)d_in[8];
  const float* f_w1    = (const float*)d_in[9];
  const float* f_b1    = (const float*)d_in[10];
  const float* f_w2    = (const float*)d_in[11];
  const float* f_b2    = (const float*)d_in[12];
  const float* g_w0    = (const float*)d_in[13];
  const float* g_b0    = (const float*)d_in[14];
  const float* g_w1    = (const float*)d_in[15];
  const float* g_b1    = (const float*)d_in[16];
  const float* g_w2    = (const float*)d_in[17];
  const float* g_b2    = (const float*)d_in[18];
  const float* wih     = (const float*)d_in[19];
  const float* whh     = (const float*)d_in[20];
  const float* bih     = (const float*)d_in[21];
  const float* bhh     = (const float*)d_in[22];
  const float* r_w0    = (const float*)d_in[23];
  const float* r_b0    = (const float*)d_in[24];
  const float* r_w1    = (const float*)d_in[25];
  const float* r_b1    = (const float*)d_in[26];
  const float* r_w2    = (const float*)d_in[27];
  const float* r_b2    = (const float*)d_in[28];
  const float* c0      = (const float*)d_in[29];
  const int*   grids   = (const int*)d_in[30];
  const int*   edges   = (const int*)d_in[31];

  float* out = (float*)d_out;
  const int iters = out_size / (BN * 9);   // = 4

  float* c    = (float*)d_ws;                        // BN*96 f32
  bf16* H0    = (bf16*)(c + (size_t)BN * 96);
  bf16* H1    = H0 + (size_t)BN * 96;
  bf16* Xg    = H1 + (size_t)BN * 96;
  bf16* P     = Xg + (size_t)BN * 96;                // BN*192
  bf16* Mb    = P  + (size_t)BN * 192;
  bf16* emb   = Mb + (size_t)BN * 96;                // BN*32
  bf16* w0pb  = emb + (size_t)BN * 32;               // 3072
  bf16* wfnb  = w0pb + 3072;                         // 18432
  bf16* inw1b = wfnb + 18432;
  bf16* inw2b = inw1b + 9216;
  bf16* fw1b  = inw2b + 9216;
  bf16* fw2b  = fw1b + 9216;
  bf16* gw0b  = fw2b + 9216;                         // 18432
  bf16* gw1b  = gw0b + 18432;
  bf16* gw2b  = gw1b + 9216;
  bf16* rw0b  = gw2b + 9216;
  bf16* rw1b  = rw0b + 9216;
  bf16* rw2b  = rw1b + 9216;                         // 864
  bf16* wihb  = rw2b + 864;                          // 36864
  bf16* whhb  = wihb + 36864;
  float* bias_fn = (float*)(whhb + 36864);           // 192 f32

  prep_k<<<dim3(144, 15), 256, 0, stream>>>(
      in_w1, in_w2, f_w1, f_w2, g_w1, g_w2, r_w0, r_w1, r_w2, wih, whh, g_w0,
      f_w0, in_w0, f_b0,
      inw1b, inw2b, fw1b, fw2b, gw1b, gw2b, rw0b, rw1b, rw2b, wihb, whhb, gw0b,
      wfnb, w0pb, bias_fn);
  embed_k<<<(BN * 32) / 256, 256, 0, stream>>>(embed, grids, emb);
  fused_in_k<<<BN / 32, 256, 0, stream>>>(emb, w0pb, in_b0, inw1b, in_b1, inw2b, in_b2,
                                          gw0b, g_b0, wfnb, bias_fn, H0, Xg, P);
  hipMemcpyAsync(c, c0, (size_t)BN * 96 * sizeof(float), hipMemcpyDeviceToDevice, stream);

  for (int it = 0; it < iters; ++it) {
    bf16* Hin  = (it & 1) ? H1 : H0;
    bf16* Hout = (it & 1) ? H0 : H1;
    edge_k<<<BN / 8, 256, 0, stream>>>(P, fw1b, f_b1, edges, fw2b, f_b2, Mb);
    fused_iter_k<<<BN / 16, 384, 0, stream>>>(
        Mb, gw0b, Xg, gw1b, g_b1, gw2b, g_b2,
        Hin, wihb, whhb, bih, bhh, c, Hout,
        wfnb, bias_fn, P, rw0b, r_b0, rw1b, r_b1, rw2b, r_b2,
        out + (size_t)it * BN * 9, it < iters - 1 ? 1 : 0);
  }
}

// Round 11
// 331.572 us; speedup vs baseline: 1.0433x; 1.0433x over previous
//
#include <hip/hip_runtime.h>
#include <hip/hip_bf16.h>

typedef __hip_bfloat16 bf16;
typedef __attribute__((ext_vector_type(8))) short short8;
typedef __attribute__((ext_vector_type(8))) __bf16 bf16x8;
typedef __attribute__((ext_vector_type(4))) float f32x4;

#define BN 20736      // 256*81
#define NNODE 81
#define KNB 20

__device__ inline float bf2f(short s) {
  union { unsigned u; float f; } x; x.u = ((unsigned)(unsigned short)s) << 16; return x.f;
}
__device__ inline short f2bf(float f) {
  __hip_bfloat16 h = __float2bfloat16(f);
  return *reinterpret_cast<short*>(&h);
}
__device__ inline bf16x8 ld8(const bf16* p) {
  return __builtin_bit_cast(bf16x8, *(const short8*)p);
}

// ---------- 48-col helpers: wave owns 16 rows x 48 cols (n0) ----------
__device__ inline void zacc3(f32x4 acc[3]) {
  #pragma unroll
  for (int nt = 0; nt < 3; ++nt) acc[nt] = (f32x4){0.f, 0.f, 0.f, 0.f};
}
__device__ inline void load_w48(const bf16* __restrict__ W, int ldw, int n0, int lr, int lq,
                                bf16x8 wf[3][3]) {
  #pragma unroll
  for (int nt = 0; nt < 3; ++nt)
    #pragma unroll
    for (int ks = 0; ks < 3; ++ks)
      wf[nt][ks] = ld8(&W[(size_t)(n0 + nt * 16 + lr) * ldw + ks * 32 + lq * 8]);
}
__device__ inline void gemm48(const bf16x8 af[3], const bf16x8 wf[3][3], f32x4 acc[3]) {
  #pragma unroll
  for (int ks = 0; ks < 3; ++ks)
    #pragma unroll
    for (int nt = 0; nt < 3; ++nt)
      acc[nt] = __builtin_amdgcn_mfma_f32_16x16x32_bf16(af[ks], wf[nt][ks], acc[nt], 0, 0, 0);
}
__device__ inline void acc_store_cs(float* xw, const f32x4 acc[3], int lr, int lq, int n0) {
  #pragma unroll
  for (int nt = 0; nt < 3; ++nt)
    #pragma unroll
    for (int r = 0; r < 4; ++r)
      xw[(lq * 4 + r) * 100 + n0 + nt * 16 + lr] = acc[nt][r];
}
__device__ inline void xbuf_frag(const float* xw, int lr, int lq,
                                 const float* __restrict__ bias, float bscale,
                                 const bf16* residRow, int act,
                                 bf16x8 af[3]) {
  #pragma unroll
  for (int ks = 0; ks < 3; ++ks) {
    const int c0 = ks * 32 + lq * 8;
    float4 x0 = *(const float4*)&xw[lr * 100 + c0];
    float4 x1 = *(const float4*)&xw[lr * 100 + c0 + 4];
    float xv[8] = {x0.x, x0.y, x0.z, x0.w, x1.x, x1.y, x1.z, x1.w};
    if (bias) {
      float4 b0 = *(const float4*)&bias[c0];
      float4 b1 = *(const float4*)&bias[c0 + 4];
      float bv[8] = {b0.x, b0.y, b0.z, b0.w, b1.x, b1.y, b1.z, b1.w};
      #pragma unroll
      for (int j = 0; j < 8; ++j) xv[j] += bscale * bv[j];
    }
    if (residRow) {
      short8 r8 = *(const short8*)&residRow[c0];
      #pragma unroll
      for (int j = 0; j < 8; ++j) xv[j] += bf2f(r8[j]);
    }
    short8 o;
    #pragma unroll
    for (int j = 0; j < 8; ++j) {
      float v = xv[j];
      if (act) v = fmaxf(v, 0.f);
      o[j] = f2bf(v);
    }
    af[ks] = __builtin_bit_cast(bf16x8, o);
  }
}
__device__ inline void store_frag(bf16* dst, int lq, const bf16x8 af[3]) {
  #pragma unroll
  for (int ks = 0; ks < 3; ++ks)
    *(short8*)&dst[ks * 32 + lq * 8] = __builtin_bit_cast(short8, af[ks]);
}

// ================= prologue: convert/build all weights =================
__global__ __launch_bounds__(256) void prep_k(
    const float* in_w1, const float* in_w2, const float* f_w1, const float* f_w2,
    const float* g_w1, const float* g_w2, const float* r_w0, const float* r_w1,
    const float* r_w2, const float* wih, const float* whh, const float* g_w0,
    const float* f_w0, const float* in_w0, const float* f_b0,
    bf16* inw1b, bf16* inw2b, bf16* fw1b, bf16* fw2b,
    bf16* gw1b, bf16* gw2b, bf16* rw0b, bf16* rw1b,
    bf16* rw2b, bf16* wihb, bf16* whhb, bf16* gw0b,
    bf16* wfnb, bf16* w0pb, float* bias_fn)
{
  int idx = blockIdx.x * 256 + threadIdx.x;
  int y = blockIdx.y;
  const float* src = nullptr; bf16* dst = nullptr; int cnt = 0;
  switch (y) {
    case 0:  src = in_w1; dst = inw1b; cnt = 9216;  break;
    case 1:  src = in_w2; dst = inw2b; cnt = 9216;  break;
    case 2:  src = f_w1;  dst = fw1b;  cnt = 9216;  break;
    case 3:  src = f_w2;  dst = fw2b;  cnt = 9216;  break;
    case 4:  src = g_w1;  dst = gw1b;  cnt = 9216;  break;
    case 5:  src = g_w2;  dst = gw2b;  cnt = 9216;  break;
    case 6:  src = r_w0;  dst = rw0b;  cnt = 9216;  break;
    case 7:  src = r_w1;  dst = rw1b;  cnt = 9216;  break;
    case 8:  src = r_w2;  dst = rw2b;  cnt = 864;   break;
    case 9:  src = wih;   dst = wihb;  cnt = 36864; break;
    case 10: src = whh;   dst = whhb;  cnt = 36864; break;
    case 11: src = g_w0;  dst = gw0b;  cnt = 18432; break;
    case 12: {
      if (idx < 18432) {
        int n = idx / 96, k = idx - n * 96;
        float v = (n < 96) ? f_w0[n * 192 + k] : f_w0[(n - 96) * 192 + 96 + k];
        wfnb[idx] = __float2bfloat16(v);
      }
      return;
    }
    case 13: {
      if (idx < 3072) {
        int n = idx >> 5, k = idx & 31;
        w0pb[idx] = __float2bfloat16(k < 16 ? in_w0[n * 16 + k] : 0.f);
      }
      return;
    }
    default: {
      if (idx < 192) bias_fn[idx] = (idx < 96) ? f_b0[idx] : 0.f;
      return;
    }
  }
  if (idx < cnt) dst[idx] = __float2bfloat16(src[idx]);
}

__global__ __launch_bounds__(256) void embed_k(const float* __restrict__ embed,
                                               const int* __restrict__ grids,
                                               bf16* __restrict__ emb) {
  int idx = blockIdx.x * 256 + threadIdx.x;
  if (idx >= BN * 32) return;
  int r = idx >> 5, k = idx & 31;
  emb[idx] = __float2bfloat16(k < 16 ? embed[grids[r] * 16 + k] : 0.f);
}

// ================= fused input chain (R9) =================
__global__ __launch_bounds__(256) void fused_in_k(
    const bf16* __restrict__ emb, const bf16* __restrict__ w0pb, const float* __restrict__ in_b0,
    const bf16* __restrict__ inw1b, const float* __restrict__ in_b1,
    const bf16* __restrict__ inw2b, const float* __restrict__ in_b2,
    const bf16* __restrict__ gw0b, const float* __restrict__ g_b0,
    const bf16* __restrict__ wfnb, const float* __restrict__ bias_fn,
    bf16* __restrict__ X, bf16* __restrict__ Xg, bf16* __restrict__ P)
{
  __shared__ float xbuf[2][2][1600];
  const int t = threadIdx.x, w = t >> 6, lane = t & 63, lr = lane & 15, lq = lane >> 4;
  const int mh = w >> 1, ch = w & 1, n0 = ch * 48;
  const int m0 = blockIdx.x * 32 + mh * 16;
  float* x0 = xbuf[0][mh];
  float* x1 = xbuf[1][mh];
  bf16x8 wf[3][3]; f32x4 acc[3]; bf16x8 af[3];

  bf16x8 a0 = ld8(&emb[(size_t)(m0 + lr) * 32 + lq * 8]);
  #pragma unroll
  for (int nt = 0; nt < 3; ++nt)
    wf[nt][0] = ld8(&w0pb[(size_t)(n0 + nt * 16 + lr) * 32 + lq * 8]);
  zacc3(acc);
  #pragma unroll
  for (int nt = 0; nt < 3; ++nt)
    acc[nt] = __builtin_amdgcn_mfma_f32_16x16x32_bf16(a0, wf[nt][0], acc[nt], 0, 0, 0);
  acc_store_cs(x0, acc, lr, lq, n0);
  __syncthreads();
  xbuf_frag(x0, lr, lq, in_b0, 1.f, nullptr, 1, af);
  load_w48(inw1b, 96, n0, lr, lq, wf); zacc3(acc); gemm48(af, wf, acc);
  acc_store_cs(x1, acc, lr, lq, n0);
  __syncthreads();
  xbuf_frag(x1, lr, lq, in_b1, 1.f, nullptr, 1, af);
  load_w48(inw2b, 96, n0, lr, lq, wf); zacc3(acc); gemm48(af, wf, acc);
  acc_store_cs(x0, acc, lr, lq, n0);
  __syncthreads();
  bf16x8 xf[3];
  xbuf_frag(x0, lr, lq, in_b2, 1.f, nullptr, 0, xf);
  if (ch == 0) store_frag(&X[(size_t)(m0 + lr) * 96], lq, xf);
  load_w48(gw0b, 192, n0, lr, lq, wf); zacc3(acc); gemm48(xf, wf, acc);
  acc_store_cs(x1, acc, lr, lq, n0);
  __syncthreads();
  xbuf_frag(x1, lr, lq, g_b0, 1.f, nullptr, 0, af);
  if (ch == 0) store_frag(&Xg[(size_t)(m0 + lr) * 96], lq, af);
  #pragma unroll
  for (int ph = 0; ph < 2; ++ph) {
    float* xb = ph ? x1 : x0;
    load_w48(wfnb + (size_t)ph * 96 * 96, 96, n0, lr, lq, wf); zacc3(acc); gemm48(xf, wf, acc);
    acc_store_cs(xb, acc, lr, lq, n0);
    __syncthreads();
    xbuf_frag(xb, lr, lq, bias_fn + ph * 96, 1.f, nullptr, 0, af);
    if (ch == 0) store_frag(&P[(size_t)(m0 + lr) * 192 + ph * 96], lq, af);
  }
}

// ================= edge kernel: XCD swizzle + hoisted W1 frags =================
__global__ __launch_bounds__(256) void edge_k(
    const bf16* __restrict__ P, const bf16* __restrict__ w1bf,
    const float* __restrict__ b1, const int* __restrict__ edges,
    const bf16* __restrict__ fw2b, const float* __restrict__ f_b2,
    bf16* __restrict__ M)
{
  __shared__ short zs[160 * 104];
  __shared__ short sbuf[16 * 104];
  const int t = threadIdx.x;
  const int swz = (blockIdx.x & 7) * 324 + (blockIdx.x >> 3);   // 2592 = 8*324, bijective
  const int ng0 = swz * 2;
  const int w = t >> 6, lane = t & 63, lr = lane & 15, lq = lane >> 4;
  const int g = w >> 1, ch = w & 1, n0 = ch * 48, zb = g * 80;

  // hoisted W1 fragment loads — overlap with Z build below
  bf16x8 wf[3][3];
  #pragma unroll
  for (int nt = 0; nt < 3; ++nt)
    #pragma unroll
    for (int ks = 0; ks < 3; ++ks)
      wf[nt][ks] = ld8(&w1bf[(size_t)(n0 + nt * 16 + lr) * 96 + ks * 32 + lq * 8]);

  for (int i = t; i < 8 * 104; i += 256) sbuf[(8 + i / 104) * 104 + (i % 104)] = 0;
  for (int cc = t; cc < 160 * 12; cc += 256) {
    int zrow = cc / 12, c8 = cc - zrow * 12;
    int gg = zrow >= 80 ? 1 : 0;
    int row = zrow - gg * 80;
    int p = row / 20, j = row - p * 20;
    int gr = (ng0 + gg) * 4 + p;
    int b = gr / NNODE, i = gr - b * NNODE;
    int e = edges[i * KNB + j];
    short8 a8 = *(const short8*)&P[(size_t)gr * 192 + c8 * 8];
    short8 n8 = *(const short8*)&P[((size_t)b * NNODE + e) * 192 + 96 + c8 * 8];
    short8 z;
    #pragma unroll
    for (int q = 0; q < 8; ++q)
      z[q] = f2bf(fmaxf(bf2f(a8[q]) + bf2f(n8[q]), 0.f));
    *(short8*)&zs[zrow * 104 + c8 * 8] = z;
  }
  __syncthreads();

  f32x4 acc[5][3];
  #pragma unroll
  for (int mt = 0; mt < 5; ++mt)
    #pragma unroll
    for (int nt = 0; nt < 3; ++nt) acc[mt][nt] = (f32x4){0.f, 0.f, 0.f, 0.f};

  #pragma unroll
  for (int ks = 0; ks < 3; ++ks) {
    const int koff = ks * 32 + lq * 8;
    #pragma unroll
    for (int mt = 0; mt < 5; ++mt) {
      bf16x8 af = __builtin_bit_cast(bf16x8, *(const short8*)&zs[(zb + mt * 16 + lr) * 104 + koff]);
      #pragma unroll
      for (int nt = 0; nt < 3; ++nt)
        acc[mt][nt] = __builtin_amdgcn_mfma_f32_16x16x32_bf16(af, wf[nt][ks], acc[mt][nt], 0, 0, 0);
    }
  }

  float bv[3];
  #pragma unroll
  for (int nt = 0; nt < 3; ++nt) bv[nt] = b1[n0 + nt * 16 + lr];
  float nodeacc[4][3];
  #pragma unroll
  for (int pp = 0; pp < 4; ++pp)
    #pragma unroll
    for (int nt = 0; nt < 3; ++nt) nodeacc[pp][nt] = 0.f;
  #pragma unroll
  for (int mt = 0; mt < 5; ++mt)
    #pragma unroll
    for (int nt = 0; nt < 3; ++nt)
      #pragma unroll
      for (int r = 0; r < 4; ++r) {
        int row = mt * 16 + lq * 4 + r;
        int p = row / 20;
        float v = fmaxf(acc[mt][nt][r] + bv[nt], 0.f);
        #pragma unroll
        for (int pp = 0; pp < 4; ++pp)
          nodeacc[pp][nt] += (p == pp) ? v : 0.f;
      }
  #pragma unroll
  for (int pp = 0; pp < 4; ++pp)
    #pragma unroll
    for (int nt = 0; nt < 3; ++nt) {
      float v = nodeacc[pp][nt];
      v += __shfl_xor(v, 16, 64);
      v += __shfl_xor(v, 32, 64);
      if (lq == 0)
        sbuf[(g * 4 + pp) * 104 + n0 + nt * 16 + lr] = f2bf(v);
    }
  __syncthreads();
  if (w < 2) {
    const int mn0 = w * 48;
    bf16x8 mwf[3][3];
    #pragma unroll
    for (int nt = 0; nt < 3; ++nt)
      #pragma unroll
      for (int ks = 0; ks < 3; ++ks)
        mwf[nt][ks] = ld8(&fw2b[(size_t)(mn0 + nt * 16 + lr) * 96 + ks * 32 + lq * 8]);
    f32x4 macc[3];
    zacc3(macc);
    #pragma unroll
    for (int ks = 0; ks < 3; ++ks) {
      bf16x8 af = __builtin_bit_cast(bf16x8, *(const short8*)&sbuf[lr * 104 + ks * 32 + lq * 8]);
      #pragma unroll
      for (int nt = 0; nt < 3; ++nt)
        macc[nt] = __builtin_amdgcn_mfma_f32_16x16x32_bf16(af, mwf[nt][ks], macc[nt], 0, 0, 0);
    }
    #pragma unroll
    for (int nt = 0; nt < 3; ++nt) {
      int col = mn0 + nt * 16 + lr;
      float bb = (float)KNB * f_b2[col];
      #pragma unroll
      for (int r = 0; r < 4; ++r) {
        int row = lq * 4 + r;
        if (row < 8)
          M[(size_t)(ng0 * 4 + row) * 96 + col] = __float2bfloat16(macc[nt][r] + bb);
      }
    }
  }
}

// ===== fused iteration kernel: 2-wave blocks (16 rows), pipelined W prefetch =====
__global__ __launch_bounds__(128) void fused_iter_k(
    const bf16* __restrict__ Min,
    const bf16* __restrict__ gw0b, const bf16* __restrict__ Xg,
    const bf16* __restrict__ gw1b, const float* __restrict__ g_b1,
    const bf16* __restrict__ gw2b, const float* __restrict__ g_b2,
    const bf16* __restrict__ Hin,
    const bf16* __restrict__ wihb, const bf16* __restrict__ whhb,
    const float* __restrict__ bih, const float* __restrict__ bhh,
    float* __restrict__ c, bf16* __restrict__ Hout,
    const bf16* __restrict__ wfnb, const float* __restrict__ bias_fn, bf16* __restrict__ P,
    const bf16* __restrict__ rw0b, const float* __restrict__ r_b0,
    const bf16* __restrict__ rw1b, const float* __restrict__ r_b1,
    const bf16* __restrict__ rw2b, const float* __restrict__ r_b2,
    float* __restrict__ outp, int doP)
{
  __shared__ float xb0[1600], xb1[1600];
  const int t = threadIdx.x, w = t >> 6, lane = t & 63, lr = lane & 15, lq = lane >> 4;
  const int n0 = w * 48;
  const int m0 = blockIdx.x * 16;

  bf16x8 wfA[3][3], wfB[3][3], af[3];
  f32x4 acc[3];

  // hoisted global A-reads
  #pragma unroll
  for (int ks = 0; ks < 3; ++ks)
    af[ks] = ld8(&Min[(size_t)(m0 + lr) * 96 + ks * 32 + lq * 8]);
  bf16x8 hin[3];
  #pragma unroll
  for (int ks = 0; ks < 3; ++ks)
    hin[ks] = ld8(&Hin[(size_t)(m0 + lr) * 96 + ks * 32 + lq * 8]);

  // S1: Min @ g_w0[:,96:]^T
  load_w48(gw0b + 96, 192, n0, lr, lq, wfA);
  zacc3(acc); gemm48(af, wfA, acc);
  load_w48(gw1b, 96, n0, lr, lq, wfB);          // prefetch S2
  acc_store_cs(xb0, acc, lr, lq, n0);
  __syncthreads();                               // B1
  xbuf_frag(xb0, lr, lq, nullptr, 0.f, &Xg[(size_t)(m0 + lr) * 96], 1, af);
  // S2: z1 @ g_w1^T
  zacc3(acc); gemm48(af, wfB, acc);
  load_w48(gw2b, 96, n0, lr, lq, wfA);           // prefetch S3
  acc_store_cs(xb1, acc, lr, lq, n0);
  __syncthreads();                               // B2
  xbuf_frag(xb1, lr, lq, g_b1, 1.f, nullptr, 1, af);
  // S3: z2 @ g_w2^T
  zacc3(acc); gemm48(af, wfA, acc);
  acc_store_cs(xb0, acc, lr, lq, n0);
  __syncthreads();                               // B3
  bf16x8 gf[3];
  xbuf_frag(xb0, lr, lq, g_b2, 1.f, nullptr, 0, gf);

  // prefetch c (used in LSTM epilogue; overlaps the 72-MFMA gate block)
  float cv[3][4];
  #pragma unroll
  for (int nt = 0; nt < 3; ++nt)
    #pragma unroll
    for (int r = 0; r < 4; ++r)
      cv[nt][r] = c[(size_t)(m0 + lq * 4 + r) * 96 + n0 + nt * 16 + lr];

  // LSTM: 4 gates x this wave's 48 cols
  f32x4 ga[4][3];
  #pragma unroll
  for (int g4 = 0; g4 < 4; ++g4)
    #pragma unroll
    for (int nt = 0; nt < 3; ++nt) ga[g4][nt] = (f32x4){0.f, 0.f, 0.f, 0.f};
  #pragma unroll
  for (int g4 = 0; g4 < 4; ++g4)
    #pragma unroll
    for (int nt = 0; nt < 3; ++nt) {
      size_t nrow = (size_t)(g4 * 96 + n0 + nt * 16 + lr) * 96;
      #pragma unroll
      for (int ks = 0; ks < 3; ++ks) {
        ga[g4][nt] = __builtin_amdgcn_mfma_f32_16x16x32_bf16(
            gf[ks], ld8(&wihb[nrow + ks * 32 + lq * 8]), ga[g4][nt], 0, 0, 0);
        ga[g4][nt] = __builtin_amdgcn_mfma_f32_16x16x32_bf16(
            hin[ks], ld8(&whhb[nrow + ks * 32 + lq * 8]), ga[g4][nt], 0, 0, 0);
      }
    }
  #pragma unroll
  for (int nt = 0; nt < 3; ++nt) {
    int col = n0 + nt * 16 + lr;
    float bvi = bih[col] + bhh[col];
    float bvf = bih[96 + col] + bhh[96 + col];
    float bvg = bih[192 + col] + bhh[192 + col];
    float bvo = bih[288 + col] + bhh[288 + col];
    #pragma unroll
    for (int r = 0; r < 4; ++r) {
      int m = m0 + lq * 4 + r;
      size_t idx = (size_t)m * 96 + col;
      float gi = ga[0][nt][r] + bvi;
      float gfv = ga[1][nt][r] + bvf;
      float gg = ga[2][nt][r] + bvg;
      float go = ga[3][nt][r] + bvo;
      float si = 1.f / (1.f + expf(-gi));
      float sf = 1.f / (1.f + expf(-gfv));
      float so = 1.f / (1.f + expf(-go));
      float tg = tanhf(gg);
      float cn = sf * cv[nt][r] + si * tg;
      if (doP) c[idx] = cn;
      xb1[(lq * 4 + r) * 100 + col] = so * tanhf(cn);
    }
  }
  __syncthreads();                               // B4
  bf16x8 hf[3];
  xbuf_frag(xb1, lr, lq, nullptr, 0.f, nullptr, 0, hf);

  if (doP) {
    // co-op coalesced Hout write from xb1
    for (int cc = t; cc < 192; cc += 128) {
      int row = cc / 12, c8 = cc - row * 12;
      short8 o;
      #pragma unroll
      for (int j = 0; j < 8; ++j) o[j] = f2bf(xb1[row * 100 + c8 * 8 + j]);
      *(short8*)&Hout[(size_t)(m0 + row) * 96 + c8 * 8] = o;
    }
    // P half 0
    load_w48(wfnb, 96, n0, lr, lq, wfA);
    zacc3(acc); gemm48(hf, wfA, acc);
    load_w48(wfnb + 96 * 96, 96, n0, lr, lq, wfB);   // prefetch P1
    #pragma unroll
    for (int nt = 0; nt < 3; ++nt) {
      float bvv = bias_fn[n0 + nt * 16 + lr];
      #pragma unroll
      for (int r = 0; r < 4; ++r)
        xb0[(lq * 4 + r) * 100 + n0 + nt * 16 + lr] = acc[nt][r] + bvv;
    }
    __syncthreads();                             // B5
    for (int cc = t; cc < 192; cc += 128) {
      int row = cc / 12, c8 = cc - row * 12;
      short8 o;
      #pragma unroll
      for (int j = 0; j < 8; ++j) o[j] = f2bf(xb0[row * 100 + c8 * 8 + j]);
      *(short8*)&P[(size_t)(m0 + row) * 192 + c8 * 8] = o;
    }
    // P half 1
    zacc3(acc); gemm48(hf, wfB, acc);
    #pragma unroll
    for (int nt = 0; nt < 3; ++nt) {
      float bvv = bias_fn[96 + n0 + nt * 16 + lr];
      #pragma unroll
      for (int r = 0; r < 4; ++r)
        xb1[(lq * 4 + r) * 100 + n0 + nt * 16 + lr] = acc[nt][r] + bvv;
    }
    __syncthreads();                             // B6
    for (int cc = t; cc < 192; cc += 128) {
      int row = cc / 12, c8 = cc - row * 12;
      short8 o;
      #pragma unroll
      for (int j = 0; j < 8; ++j) o[j] = f2bf(xb1[row * 100 + c8 * 8 + j]);
      *(short8*)&P[(size_t)(m0 + row) * 192 + 96 + c8 * 8] = o;
    }
  }

  // r-MLP
  load_w48(rw0b, 96, n0, lr, lq, wfA);
  zacc3(acc); gemm48(hf, wfA, acc);
  load_w48(rw1b, 96, n0, lr, lq, wfB);           // prefetch
  __syncthreads();                               // B7 (prev xb0/xb1 readers done)
  acc_store_cs(xb0, acc, lr, lq, n0);
  __syncthreads();                               // B8
  xbuf_frag(xb0, lr, lq, r_b0, 1.f, nullptr, 1, af);
  zacc3(acc); gemm48(af, wfB, acc);
  acc_store_cs(xb1, acc, lr, lq, n0);
  __syncthreads();                               // B9
  xbuf_frag(xb1, lr, lq, r_b1, 1.f, nullptr, 1, af);
  if (w == 0) {
    bf16x8 w9[3];
    #pragma unroll
    for (int ks = 0; ks < 3; ++ks) {
      short8 s = {0, 0, 0, 0, 0, 0, 0, 0};
      if (lr < 9) s = *(const short8*)&rw2b[(size_t)lr * 96 + ks * 32 + lq * 8];
      w9[ks] = __builtin_bit_cast(bf16x8, s);
    }
    f32x4 a9 = (f32x4){0.f, 0.f, 0.f, 0.f};
    #pragma unroll
    for (int ks = 0; ks < 3; ++ks)
      a9 = __builtin_amdgcn_mfma_f32_16x16x32_bf16(af[ks], w9[ks], a9, 0, 0, 0);
    if (lr < 9) {
      float bb = r_b2[lr];
      #pragma unroll
      for (int r = 0; r < 4; ++r)
        outp[(size_t)(m0 + lq * 4 + r) * 9 + lr] = a9[r] + bb;
    }
  }
}

// ================= host side =================
extern "C" void kernel_launch(void* const* d_in, const int* in_sizes, int n_in,
                              void* d_out, int out_size, void* d_ws, size_t ws_size,
                              hipStream_t stream) {
  const float* embed   = (const float*)d_in[0];
  const float* in_w0   = (const float*)d_in[1];
  const float* in_b0   = (const float*)d_in[2];
  const float* in_w1   = (const float*)d_in[3];
  const float* in_b1   = (const float*)d_in[4];
  const float* in_w2   = (const float*)d_in[5];
  const float* in_b2   = (const float*)d_in[6];
  const float* f_w0    = (const float*)d_in[7];
  const float* f_b0    = (const float*)d_in[8];
  const float* f_w1    = (const float*)d_in[9];
  const float* f_b1    = (const float*)d_in[10];
  const float* f_w2    = (const float*)d_in[11];
  const float* f_b2    = (const float*)d_in[12];
  const float* g_w0    = (const float*)d_in[13];
  const float* g_b0    = (const float*)d_in[14];
  const float* g_w1    = (const float*)d_in[15];
  const float* g_b1    = (const float*)d_in[16];
  const float* g_w2    = (const float*)d_in[17];
  const float* g_b2    = (const float*)d_in[18];
  const float* wih     = (const float*)d_in[19];
  const float* whh     = (const float*)d_in[20];
  const float* bih     = (const float*)d_in[21];
  const float* bhh     = (const float*)d_in[22];
  const float* r_w0    = (const float*)d_in[23];
  const float* r_b0    = (const float*)d_in[24];
  const float* r_w1    = (const float*)d_in[25];
  const float* r_b1    = (const float*)d_in[26];
  const float* r_w2    = (const float*)d_in[27];
  const float* r_b2    = (const float*)d_in[28];
  const float* c0      = (const float*)d_in[29];
  const int*   grids   = (const int*)d_in[30];
  const int*   edges   = (const int*)d_in[31];

  float* out = (float*)d_out;
  const int iters = out_size / (BN * 9);   // = 4

  float* c    = (float*)d_ws;                        // BN*96 f32
  bf16* H0    = (bf16*)(c + (size_t)BN * 96);
  bf16* H1    = H0 + (size_t)BN * 96;
  bf16* Xg    = H1 + (size_t)BN * 96;
  bf16* P     = Xg + (size_t)BN * 96;                // BN*192
  bf16* Mb    = P  + (size_t)BN * 192;
  bf16* emb   = Mb + (size_t)BN * 96;                // BN*32
  bf16* w0pb  = emb + (size_t)BN * 32;               // 3072
  bf16* wfnb  = w0pb + 3072;                         // 18432
  bf16* inw1b = wfnb + 18432;
  bf16* inw2b = inw1b + 9216;
  bf16* fw1b  = inw2b + 9216;
  bf16* fw2b  = fw1b + 9216;
  bf16* gw0b  = fw2b + 9216;                         // 18432
  bf16* gw1b  = gw0b + 18432;
  bf16* gw2b  = gw1b + 9216;
  bf16* rw0b  = gw2b + 9216;
  bf16* rw1b  = rw0b + 9216;
  bf16* rw2b  = rw1b + 9216;                         // 864
  bf16* wihb  = rw2b + 864;                          // 36864
  bf16* whhb  = wihb + 36864;
  float* bias_fn = (float*)(whhb + 36864);           // 192 f32

  prep_k<<<dim3(144, 15), 256, 0, stream>>>(
      in_w1, in_w2, f_w1, f_w2, g_w1, g_w2, r_w0, r_w1, r_w2, wih, whh, g_w0,
      f_w0, in_w0, f_b0,
      inw1b, inw2b, fw1b, fw2b, gw1b, gw2b, rw0b, rw1b, rw2b, wihb, whhb, gw0b,
      wfnb, w0pb, bias_fn);
  embed_k<<<(BN * 32) / 256, 256, 0, stream>>>(embed, grids, emb);
  fused_in_k<<<BN / 32, 256, 0, stream>>>(emb, w0pb, in_b0, inw1b, in_b1, inw2b, in_b2,
                                          gw0b, g_b0, wfnb, bias_fn, H0, Xg, P);
  hipMemcpyAsync(c, c0, (size_t)BN * 96 * sizeof(float), hipMemcpyDeviceToDevice, stream);

  for (int it = 0; it < iters; ++it) {
    bf16* Hin  = (it & 1) ? H1 : H0;
    bf16* Hout = (it & 1) ? H0 : H1;
    edge_k<<<BN / 8, 256, 0, stream>>>(P, fw1b, f_b1, edges, fw2b, f_b2, Mb);
    fused_iter_k<<<BN / 16, 128, 0, stream>>>(
        Mb, gw0b, Xg, gw1b, g_b1, gw2b, g_b2,
        Hin, wihb, whhb, bih, bhh, c, Hout,
        wfnb, bias_fn, P, rw0b, r_b0, rw1b, r_b1, rw2b, r_b2,
        out + (size_t)it * BN * 9, it < iters - 1 ? 1 : 0);
  }
}